// Round 7
// baseline (1987.937 us; speedup 1.0000x reference)
//
#include <hip/hip_runtime.h>
#include <math.h>

// Problem constants
#define B_     8
#define S_     4
#define H_     50
#define NH_    200
#define EHH_   400
#define L_     2
#define HID_   128
#define FDIM_  79          // 44 + 20 + 15
#define EDIM_  161         // 2*FDIM + 3
#define NN_    250         // H + NH
#define NE_    10400       // EHH + H*NH
#define BS_    32          // B*S
#define TOTE_  (BS_*NE_)   // 332800
#define FS_    80          // feat row stride
#define TE_    64          // edges per tile
#define MSTR_  136         // s_m stride in bf16 (128 + 8)
#define NDIM_  207         // FDIM + HID
#define NTILES_ (TOTE_/TE_)  // 5200
// 768 blocks = 3 blocks/CU x 256 CUs. Guaranteed co-resident:
// __launch_bounds__(256,3) caps VGPR<=170; LDS 3x24576=73728<=160K; 12 waves/CU<=32.
#define NBLK_  768

// Workspace layout (float offsets)
#define OFF_FEATH  0         // BS*H*80 = 128000
#define OFF_X      128000    // BS*NN*4 = 32000
#define OFF_X0H    160000    // BS*H*4  = 6400
#define OFF_EROW   166400    // 83200 (int)
#define OFF_ECOL   249600    // 83200 (int)
#define OFF_EMASK  332800    // 83200
#define OFF_EBOND  416000    // 83200
#define OFF_AGG0   499200    // aggx0(6400)+aggm0(204800); agg1 contiguous after
#define OFF_AGG1   710400
#define OFF_HIW1   921600    // 1600*128 (b1 + t*w160 folded in)
#define OFF_HJW1   1126400   // 4800*128: [0,1600) h cur | [1600,3200) hv l0 | [3200,4800) hv l1
#define OFF_WP     1740800   // 65536 ushort = 32768 floats
#define OFF_BAR    1773568   // 16 ints (global barrier counters, memset to 0 pre-launch)
#define AGGSTRIDE_ 211200

typedef __attribute__((ext_vector_type(8))) short short8;
typedef __attribute__((ext_vector_type(4))) float f32x4;

__device__ __forceinline__ float silu_(float v) {
    return v * __builtin_amdgcn_rcpf(1.0f + __expf(-v));
}
__device__ __forceinline__ unsigned short f2bf(float f) {
    unsigned int u = __float_as_uint(f);
    unsigned int r = (u + 0x7fffu + ((u >> 16) & 1u)) >> 16;
    return (unsigned short)r;
}
__device__ __forceinline__ float bf2f(unsigned short v) {
    return __uint_as_float(((unsigned int)v) << 16);
}

struct KParams {
    const float *t_in, *x_h, *x_hv, *bond, *em_hv, *em_hh, *amask;
    const float *W1, *b1, *W2, *b2, *Wc1, *bc1, *Wc2, *Wn1, *bn1, *Wn2, *bn2;
    const int *pep, *lab_hv, *lab_h, *pos_hv, *pos_h, *ehh, *bound;
    float *feat_h, *x, *x0h, *emk, *ebd, *agg0, *hiW1, *hjW1, *out;
    int *erow, *ecol;
    unsigned short *Wp;
    int *bar;
};

// device-scope grid barrier: single-use counter per sync point (bar[] zeroed
// by hipMemsetAsync before launch). Equivalent to cg grid.sync() internals,
// but launched as a NORMAL kernel (no cooperative-launch validation/capture issues).
__device__ __forceinline__ void gsync(int* bar, int idx)
{
    __syncthreads();
    if (threadIdx.x == 0) {
        __threadfence();   // release: make this block's writes visible device-wide
        __hip_atomic_fetch_add(&bar[idx], 1, __ATOMIC_RELEASE, __HIP_MEMORY_SCOPE_AGENT);
        while (__hip_atomic_load(&bar[idx], __ATOMIC_ACQUIRE, __HIP_MEMORY_SCOPE_AGENT) < NBLK_)
            __builtin_amdgcn_s_sleep(8);
        __threadfence();   // acquire: invalidate stale cache lines before proceeding
    }
    __syncthreads();
}

// shared-memory overlays (one 24.6 KB buffer reused by all phases)
struct EdgeSm {
    unsigned short m[TE_][MSTR_];  // 17408
    float partT[16][68];           // 4352
    float diff[TE_][4];            // 1024
    float db[TE_][2];              // 512
    float emk[TE_];                // 256
    int   ii[TE_];                 // 256
    int   jj[TE_];                 // 256
};                                 // 24064 B
struct UpdSm { float in[16][208]; float u[16][129]; };   // 21568 B
struct SortSm { int cnt[64]; int row[EHH_]; int col[EHH_]; float em[EHH_]; };

// ---------------- setup virtual blocks ----------------
#define HV_VB_    1600
#define PACK_VB_  256
#define EDGE_VB_  325
#define SORT_VB_  8
#define HROW_VB_  200
#define FEAT_VB_  125
#define ZERO_VB_  413      // 105600 float4 (both agg buffers)
#define XI_VB_    32
#define SETUP_VB_ (HV_VB_ + PACK_VB_ + EDGE_VB_ + SORT_VB_ + HROW_VB_ + FEAT_VB_ + ZERO_VB_ + XI_VB_)  // 2959

__device__ void setup_vblock(int blk, int t, const KParams& p, char* smem)
{
    if (blk < HV_VB_) {
        int g = blk*256 + t;                 // [0, 409600)
        int l = g / 204800;
        int r = g - l*204800;
        int node = r >> 7, col = r & 127;    // node = b*NH + nh
        int b = node / NH_;
        int label = p.lab_hv[node], pos = p.pos_hv[node];
        int aa = p.pep[b*15 + pos - 1];
        const float* W1l = p.W1 + l*EDIM_*HID_;
        float hj = W1l[(FDIM_ + label)*HID_ + col]
                 + W1l[(FDIM_ + 44 + aa)*HID_ + col]
                 + W1l[(FDIM_ + 64 + pos - 1)*HID_ + col];
        p.hjW1[(size_t)(1600 + l*1600 + node)*HID_ + col] = hj;
        return;
    }
    blk -= HV_VB_;
    if (blk < PACK_VB_) {
        int g = blk*256 + t;
        int idx = g & 16383;
        int lm  = g >> 14;
        int l = lm >> 1, mat = lm & 1;
        int j = idx & 7, q = (idx >> 3) & 3, n = (idx >> 5) & 127, kc = idx >> 12;
        int k = kc*32 + q*8 + j;
        const float* W = (mat == 0 ? p.W2 : p.Wc1) + l*HID_*HID_;
        p.Wp[g] = f2bf(W[k*HID_ + n]);
        return;
    }
    blk -= PACK_VB_;
    if (blk < EDGE_VB_) {
        int g = blk*256 + t;                  // [0, 83200)
        int b = g / NE_, e = g % NE_;
        if (e < EHH_) return;                 // hh edges handled by sort phase
        int k = e - EHH_;
        int r = k / NH_; int cc = k % NH_; int c = H_ + cc;
        p.erow[g] = r; p.ecol[g] = c;
        p.emk[g] = p.em_hv[(b*H_ + r)*NH_ + cc];
        p.ebd[g] = p.bond [(b*H_ + r)*NH_ + cc];
        return;
    }
    blk -= EDGE_VB_;
    if (blk < SORT_VB_) {
        // counting-sort the 400 hh edges of batch b by row
        int b = blk;
        SortSm* sm = (SortSm*)smem;
        __syncthreads();                      // protect any prior phase LDS use
        if (t < 64) sm->cnt[t] = 0;
        __syncthreads();
        for (int e = t; e < EHH_; e += 256) {
            int r = p.ehh[(b*EHH_ + e)*2 + 0];
            sm->row[e] = r;
            sm->col[e] = p.ehh[(b*EHH_ + e)*2 + 1];
            sm->em[e]  = p.em_hh[b*EHH_ + e];
            atomicAdd(&sm->cnt[r], 1);
        }
        __syncthreads();
        if (t == 0) {
            int acc = 0;
            for (int i = 0; i < H_; ++i) { int v = sm->cnt[i]; sm->cnt[i] = acc; acc += v; }
        }
        __syncthreads();
        for (int e = t; e < EHH_; e += 256) {
            int r = sm->row[e];
            int pos = atomicAdd(&sm->cnt[r], 1);
            int g = b*NE_ + pos;
            p.erow[g] = r; p.ecol[g] = sm->col[e]; p.emk[g] = sm->em[e]; p.ebd[g] = 0.0f;
        }
        __syncthreads();
        return;
    }
    blk -= SORT_VB_;
    if (blk < HROW_VB_) {
        // h-node layer-0 projections; fold b1 + t*w160 into hiW1
        int g = blk*256 + t;                 // [0, 51200)
        int node = g >> 7, col = g & 127;    // node = b*H + h
        int b = node / H_;
        int label = p.lab_h[node], pos = p.pos_h[node];
        int aa = p.pep[b*15 + pos - 1];
        const float* W1l = p.W1;
        float hi = W1l[label*HID_ + col]
                 + W1l[(44 + aa)*HID_ + col]
                 + W1l[(64 + pos - 1)*HID_ + col]
                 + p.b1[col]
                 + p.t_in[b] * W1l[160*HID_ + col];
        float hj = W1l[(FDIM_ + label)*HID_ + col]
                 + W1l[(FDIM_ + 44 + aa)*HID_ + col]
                 + W1l[(FDIM_ + 64 + pos - 1)*HID_ + col];
        int h = node % H_;
        #pragma unroll
        for (int s = 0; s < S_; ++s) {
            int row = (b*S_ + s)*H_ + h;
            p.hiW1[(size_t)row*HID_ + col] = hi;
            p.hjW1[(size_t)row*HID_ + col] = hj;
        }
        return;
    }
    blk -= HROW_VB_;
    if (blk < FEAT_VB_) {
        int g = blk*256 + t;                 // [0, 32000)
        int node = g / FS_, f = g % FS_;     // node = b*H + h
        int b = node / H_, h = node % H_;
        int label = p.lab_h[node], pos = p.pos_h[node];
        int aa = p.pep[b*15 + pos - 1];
        float v = 0.f;
        if (f < 44)      v = (f == label)          ? 1.0f : 0.0f;
        else if (f < 64) v = ((f - 44) == aa)      ? 1.0f : 0.0f;
        else if (f < 79) v = ((f - 64) == pos - 1) ? 1.0f : 0.0f;
        #pragma unroll
        for (int s = 0; s < S_; ++s)
            p.feat_h[((b*S_ + s)*H_ + h)*FS_ + f] = v;
        return;
    }
    blk -= FEAT_VB_;
    if (blk < ZERO_VB_) {
        int idx = blk*256 + t;
        if (idx < 105600) ((float4*)p.agg0)[idx] = make_float4(0.f, 0.f, 0.f, 0.f);
        return;
    }
    blk -= ZERO_VB_;
    {
        int g = blk*256 + t;
        if (g >= BS_*NN_) return;
        int bs = g / NN_, n = g % NN_;
        int b = bs / S_;
        if (n < H_) {
            int ba = p.bound[b*H_ + n];
            for (int d = 0; d < 3; ++d) {
                float v = p.x_h[(bs*H_ + n)*3 + d] + p.x_hv[(b*NH_ + ba)*3 + d];
                p.x[g*4 + d] = v;
                p.x0h[(bs*H_ + n)*4 + d] = v;
            }
        } else {
            int nh = n - H_;
            for (int d = 0; d < 3; ++d) p.x[g*4 + d] = p.x_hv[(b*NH_ + nh)*3 + d];
        }
    }
}

// ---------------- edge tile (64 edges) ----------------
__device__ void edge_tile(int tile, int t, const KParams& p, int l,
                          float* __restrict__ aggx, float* __restrict__ aggm,
                          char* smem)
{
    EdgeSm* sm = (EdgeSm*)smem;
    const int lane = t & 63, w = t >> 6;
    const int l15 = lane & 15, q = lane >> 4;

    __syncthreads();   // protect previous tile's LDS readers

    if (t < TE_) {
        int ge = tile*TE_ + t;
        int bs = ge / NE_;
        int e  = ge - bs*NE_;
        int b  = bs / S_;
        int row = p.erow[b*NE_ + e], col = p.ecol[b*NE_ + e];
        sm->ii[t] = bs*H_ + row;
        sm->jj[t] = (col < H_) ? (bs*H_ + col) : (1600 + l*1600 + b*NH_ + (col - H_));
        float dx0 = p.x[(bs*NN_ + row)*4 + 0] - p.x[(bs*NN_ + col)*4 + 0];
        float dx1 = p.x[(bs*NN_ + row)*4 + 1] - p.x[(bs*NN_ + col)*4 + 1];
        float dx2 = p.x[(bs*NN_ + row)*4 + 2] - p.x[(bs*NN_ + col)*4 + 2];
        sm->diff[t][0] = dx0; sm->diff[t][1] = dx1; sm->diff[t][2] = dx2;
        sm->db[t][0] = sqrtf(dx0*dx0 + dx1*dx1 + dx2*dx2);
        sm->db[t][1] = p.ebd[b*NE_ + e];
        sm->emk[t]   = p.emk[b*NE_ + e];
    }
    __syncthreads();

    const int mrow = w*16 + l15;

    // stage 1 (register-direct; b1 + t*w160 folded into hiW1)
    short8 afrag[4];
    {
        const float* W1l = p.W1 + l*EDIM_*HID_;
        int ri = sm->ii[mrow], rj = sm->jj[mrow];
        float dist = sm->db[mrow][0], bond = sm->db[mrow][1];
        const float* pi = p.hiW1 + (size_t)ri*HID_ + q*8;
        const float* pj = p.hjW1 + (size_t)rj*HID_ + q*8;
        #pragma unroll
        for (int kc = 0; kc < 4; ++kc) {
            int k0 = kc*32 + q*8;
            float4 a0 = *(const float4*)(pi + kc*32);
            float4 a1 = *(const float4*)(pi + kc*32 + 4);
            float4 c0 = *(const float4*)(pj + kc*32);
            float4 c1 = *(const float4*)(pj + kc*32 + 4);
            float4 wa0 = *(const float4*)(W1l + 158*HID_ + k0);
            float4 wa1 = *(const float4*)(W1l + 158*HID_ + k0 + 4);
            float4 wb0 = *(const float4*)(W1l + 159*HID_ + k0);
            float4 wb1 = *(const float4*)(W1l + 159*HID_ + k0 + 4);
            short8 fr;
            fr[0] = (short)f2bf(silu_(a0.x + c0.x + dist*wa0.x + bond*wb0.x));
            fr[1] = (short)f2bf(silu_(a0.y + c0.y + dist*wa0.y + bond*wb0.y));
            fr[2] = (short)f2bf(silu_(a0.z + c0.z + dist*wa0.z + bond*wb0.z));
            fr[3] = (short)f2bf(silu_(a0.w + c0.w + dist*wa0.w + bond*wb0.w));
            fr[4] = (short)f2bf(silu_(a1.x + c1.x + dist*wa1.x + bond*wb1.x));
            fr[5] = (short)f2bf(silu_(a1.y + c1.y + dist*wa1.y + bond*wb1.y));
            fr[6] = (short)f2bf(silu_(a1.z + c1.z + dist*wa1.z + bond*wb1.z));
            fr[7] = (short)f2bf(silu_(a1.w + c1.w + dist*wa1.w + bond*wb1.w));
            afrag[kc] = fr;
        }
    }

    // stage 2: m = silu(m1 @ W2 + b2) * emask
    {
        const unsigned short* Wp2 = p.Wp + (size_t)(l*2 + 0)*16384;
        const float* b2l = p.b2 + l*HID_;
        float em4[4];
        #pragma unroll
        for (int r = 0; r < 4; ++r) em4[r] = sm->emk[w*16 + q*4 + r];
        #pragma unroll
        for (int nt = 0; nt < 8; ++nt) {
            int colj = nt*16 + l15;
            float bias = b2l[colj];
            f32x4 c = {bias, bias, bias, bias};
            #pragma unroll
            for (int kc = 0; kc < 4; ++kc) {
                short8 bfrag = *(const short8*)&Wp2[((kc*128 + nt*16 + l15)*4 + q)*8];
                c = __builtin_amdgcn_mfma_f32_16x16x32_bf16(afrag[kc], bfrag, c, 0, 0, 0);
            }
            #pragma unroll
            for (int r = 0; r < 4; ++r)
                sm->m[w*16 + q*4 + r][colj] = f2bf(silu_(c[r]) * em4[r]);
        }
    }
    __builtin_amdgcn_wave_barrier();   // wave-private rows: ds_write before ds_read

    // stage 3: cw = silu(m @ Wc1 + bc1) @ Wc2
    {
        short8 af2[4];
        #pragma unroll
        for (int kc = 0; kc < 4; ++kc)
            af2[kc] = *(const short8*)&sm->m[mrow][kc*32 + q*8];
        const unsigned short* Wp3 = p.Wp + (size_t)(l*2 + 1)*16384;
        const float* bc1l = p.bc1 + l*HID_;
        const float* wc2l = p.Wc2 + l*HID_;
        float pp[4] = {0.f, 0.f, 0.f, 0.f};
        #pragma unroll
        for (int nt = 0; nt < 8; ++nt) {
            int colj = nt*16 + l15;
            float bias = bc1l[colj];
            f32x4 c = {bias, bias, bias, bias};
            #pragma unroll
            for (int kc = 0; kc < 4; ++kc) {
                short8 bfrag = *(const short8*)&Wp3[((kc*128 + nt*16 + l15)*4 + q)*8];
                c = __builtin_amdgcn_mfma_f32_16x16x32_bf16(af2[kc], bfrag, c, 0, 0, 0);
            }
            float wcv = wc2l[colj];
            #pragma unroll
            for (int r = 0; r < 4; ++r)
                pp[r] += silu_(c[r]) * wcv;
        }
        *(float4*)&sm->partT[l15][w*16 + q*4] = make_float4(pp[0], pp[1], pp[2], pp[3]);
    }
    __syncthreads();

    // aggregation: wave 0 = cw reduce + aggx; waves 1,2 = aggm
    if (t < TE_) {
        float cwv = 0.f;
        #pragma unroll
        for (int c = 0; c < 16; ++c) cwv += sm->partT[c][t];
        float run = 0.f; int ct = sm->ii[0];
        int d = lane & 3;
        for (int i2 = 0; i2 < TE_; ++i2) {
            float cwi = __shfl(cwv, i2, 64);
            int tg = sm->ii[i2];
            if (tg != ct) {
                if (lane < 3) atomicAdd(&aggx[(size_t)ct*4 + d], run);
                run = 0.f; ct = tg;
            }
            run += sm->diff[i2][d] * cwi;
        }
        if (lane < 3) atomicAdd(&aggx[(size_t)ct*4 + d], run);
    } else if (t < TE_ + HID_) {
        int j = t - TE_;
        float run = 0.f; int ct = sm->ii[0];
        for (int i2 = 0; i2 < TE_; ++i2) {
            int tg = sm->ii[i2];
            if (tg != ct) {
                atomicAdd(&aggm[(size_t)ct*HID_ + j], run);
                run = 0.f; ct = tg;
            }
            run += bf2f(sm->m[i2][j]);
        }
        atomicAdd(&aggm[(size_t)ct*HID_ + j], run);
    }
}

// ---------------- update (16 nodes per vblock, 256 threads) ----------------
__device__ void update_vblock(int vb, int t, const KParams& p, int l,
                              const float* __restrict__ aggm,
                              const float* __restrict__ aggx, char* smem)
{
    UpdSm* sm = (UpdSm*)smem;
    int node0 = vb * 16;                   // bs*H + h
    __syncthreads();
    for (int idx = t; idx < 16*208; idx += 256) {
        int g = idx / 208, k = idx - g*208;
        float v = 0.f;
        if (k < FDIM_)      v = p.feat_h[(node0 + g)*FS_ + k];
        else if (k < NDIM_) v = aggm[(size_t)(node0 + g)*HID_ + (k - FDIM_)];
        sm->in[g][k] = v;
    }
    __syncthreads();
    int half = t >> 7, ht = t & 127;
    int g0 = half * 8;
    const float* Wn1l = p.Wn1 + l*NDIM_*HID_;
    float acc[8];
    float bv = p.bn1[l*HID_ + ht];
    #pragma unroll
    for (int g = 0; g < 8; ++g) acc[g] = bv;
    for (int k = 0; k < NDIM_; ++k) {
        float wv = Wn1l[k*HID_ + ht];
        #pragma unroll
        for (int g = 0; g < 8; ++g) acc[g] += sm->in[g0 + g][k] * wv;
    }
    #pragma unroll
    for (int g = 0; g < 8; ++g) sm->u[g0 + g][ht] = silu_(acc[g]);
    __syncthreads();
    if (ht < FDIM_) {
        const float* Wn2l = p.Wn2 + l*HID_*FDIM_;
        float acc2[8];
        float b2v = p.bn2[l*FDIM_ + ht];
        #pragma unroll
        for (int g = 0; g < 8; ++g) acc2[g] = b2v;
        for (int k = 0; k < HID_; ++k) {
            float wv = Wn2l[k*FDIM_ + ht];
            #pragma unroll
            for (int g = 0; g < 8; ++g) acc2[g] += sm->u[g0 + g][k] * wv;
        }
        #pragma unroll
        for (int g = 0; g < 8; ++g) {
            float nf = sm->in[g0 + g][ht] + acc2[g];
            p.feat_h[(node0 + g0 + g)*FS_ + ht] = nf;
            sm->in[g0 + g][ht] = nf;
        }
    } else if (ht >= 96 && ht < 120) {
        int idx = ht - 96, g = idx / 3, d = idx % 3;
        int node = node0 + g0 + g;
        int bs = node / H_, h = node % H_;
        float xv = p.x[(bs*NN_ + h)*4 + d] + aggx[(size_t)node*4 + d];
        p.x[(bs*NN_ + h)*4 + d] = xv;
        if (l == L_ - 1) {
            int b = bs / S_;
            p.out[node*3 + d] = (xv - p.x0h[node*4 + d]) * p.amask[b*H_ + h];
        }
    }
    if (l != 0) return;
    __syncthreads();
    // next-layer W1 projections for the 16 updated h nodes (b1 + t*w160 folded)
    {
        const float* W1n = p.W1 + EDIM_*HID_;
        float w160 = W1n[160*HID_ + ht];
        float b1v  = p.b1[HID_ + ht];
        float hia[8], hja[8];
        #pragma unroll
        for (int g = 0; g < 8; ++g) { hia[g] = 0.f; hja[g] = 0.f; }
        for (int f = 0; f < FDIM_; ++f) {
            float wi = W1n[f*HID_ + ht];
            float wj = W1n[(FDIM_ + f)*HID_ + ht];
            #pragma unroll
            for (int g = 0; g < 8; ++g) {
                float v = sm->in[g0 + g][f];
                hia[g] += v * wi;
                hja[g] += v * wj;
            }
        }
        #pragma unroll
        for (int g = 0; g < 8; ++g) {
            int node = node0 + g0 + g;
            int b = (node / H_) / S_;
            p.hiW1[(size_t)node*HID_ + ht] = hia[g] + b1v + p.t_in[b]*w160;
            p.hjW1[(size_t)node*HID_ + ht] = hja[g];
        }
    }
}

// ---------------- the single persistent kernel (normal launch) ----------------
__global__ __launch_bounds__(256, 3) void k_fused(KParams p)
{
    __shared__ __align__(16) char smem[24576];
    const int t = threadIdx.x;

    for (int vb = blockIdx.x; vb < SETUP_VB_; vb += NBLK_)
        setup_vblock(vb, t, p, smem);
    gsync(p.bar, 0);

    for (int l = 0; l < L_; ++l) {
        float* aggx = p.agg0 + (size_t)l*AGGSTRIDE_;
        float* aggm = aggx + 6400;
        for (int vb = blockIdx.x; vb < NTILES_; vb += NBLK_)
            edge_tile(vb, t, p, l, aggx, aggm, smem);
        gsync(p.bar, 1 + 2*l);
        for (int vb = blockIdx.x; vb < 100; vb += NBLK_)
            update_vblock(vb, t, p, l, aggm, aggx, smem);
        if (l == 0) gsync(p.bar, 2);
    }
}

// ---------------- launch ----------------
extern "C" void kernel_launch(void* const* d_in, const int* in_sizes, int n_in,
                              void* d_out, int out_size, void* d_ws, size_t ws_size,
                              hipStream_t stream)
{
    float* ws = (float*)d_ws;
    KParams p;
    p.t_in  = (const float*)d_in[0];
    p.x_h   = (const float*)d_in[1];
    p.x_hv  = (const float*)d_in[2];
    p.bond  = (const float*)d_in[3];
    p.em_hv = (const float*)d_in[4];
    p.em_hh = (const float*)d_in[5];
    p.amask = (const float*)d_in[6];
    p.W1    = (const float*)d_in[7];
    p.b1    = (const float*)d_in[8];
    p.W2    = (const float*)d_in[9];
    p.b2    = (const float*)d_in[10];
    p.Wc1   = (const float*)d_in[11];
    p.bc1   = (const float*)d_in[12];
    p.Wc2   = (const float*)d_in[13];
    p.Wn1   = (const float*)d_in[14];
    p.bn1   = (const float*)d_in[15];
    p.Wn2   = (const float*)d_in[16];
    p.bn2   = (const float*)d_in[17];
    p.pep   = (const int*)d_in[18];
    p.lab_hv= (const int*)d_in[19];
    p.lab_h = (const int*)d_in[20];
    p.pos_hv= (const int*)d_in[21];
    p.pos_h = (const int*)d_in[22];
    p.ehh   = (const int*)d_in[23];
    p.bound = (const int*)d_in[24];
    p.feat_h = ws + OFF_FEATH;
    p.x      = ws + OFF_X;
    p.x0h    = ws + OFF_X0H;
    p.erow   = (int*)(ws + OFF_EROW);
    p.ecol   = (int*)(ws + OFF_ECOL);
    p.emk    = ws + OFF_EMASK;
    p.ebd    = ws + OFF_EBOND;
    p.agg0   = ws + OFF_AGG0;
    p.hiW1   = ws + OFF_HIW1;
    p.hjW1   = ws + OFF_HJW1;
    p.Wp     = (unsigned short*)(ws + OFF_WP);
    p.bar    = (int*)(ws + OFF_BAR);
    p.out    = (float*)d_out;

    // zero the global-barrier counters (ws is re-poisoned before every launch)
    hipMemsetAsync(p.bar, 0, 16*sizeof(int), stream);
    hipLaunchKernelGGL(k_fused, dim3(NBLK_), dim3(256), 0, stream, p);
}

// Round 8
// 1138.664 us; speedup vs baseline: 1.7459x; 1.7459x over previous
//
#include <hip/hip_runtime.h>
#include <math.h>

// Problem constants
#define B_     8
#define S_     4
#define H_     50
#define NH_    200
#define EHH_   400
#define L_     2
#define HID_   128
#define FDIM_  79          // 44 + 20 + 15
#define EDIM_  161         // 2*FDIM + 3
#define NN_    250         // H + NH
#define NE_    10400       // EHH + H*NH
#define BS_    32          // B*S
#define TOTE_  (BS_*NE_)   // 332800
#define FS_    80          // feat row stride
#define TE_    64          // edges per tile
#define MSTR_  136         // s_m stride in bf16 (128 + 8)
#define NDIM_  207         // FDIM + HID
#define NTILES_ (TOTE_/TE_)  // 5200
// 768 blocks = 3 blocks/CU x 256 CUs. Guaranteed co-resident:
// __launch_bounds__(256,3) caps VGPR<=170; LDS 3x24576=73728<=160K; 12 waves/CU<=32.
#define NBLK_  768

// Workspace layout (float offsets)
#define OFF_FEATH  0         // BS*H*80 = 128000
#define OFF_X      128000    // BS*NN*4 = 32000
#define OFF_X0H    160000    // BS*H*4  = 6400
#define OFF_EROW   166400    // 83200 (int)
#define OFF_ECOL   249600    // 83200 (int)
#define OFF_EMASK  332800    // 83200
#define OFF_EBOND  416000    // 83200
#define OFF_AGG0   499200    // aggx0(6400)+aggm0(204800); agg1 contiguous after
#define OFF_AGG1   710400
#define OFF_HIW1   921600    // 1600*128 (b1 + t*w160 folded in)
#define OFF_HJW1   1126400   // 4800*128: [0,1600) h cur | [1600,3200) hv l0 | [3200,4800) hv l1
#define OFF_WP     1740800   // 65536 ushort = 32768 floats
#define OFF_BAR    1773568   // 16 ints (global barrier counters, memset to 0 pre-launch)
#define AGGSTRIDE_ 211200

typedef __attribute__((ext_vector_type(8))) short short8;
typedef __attribute__((ext_vector_type(4))) float f32x4;

__device__ __forceinline__ float silu_(float v) {
    return v * __builtin_amdgcn_rcpf(1.0f + __expf(-v));
}
__device__ __forceinline__ unsigned short f2bf(float f) {
    unsigned int u = __float_as_uint(f);
    unsigned int r = (u + 0x7fffu + ((u >> 16) & 1u)) >> 16;
    return (unsigned short)r;
}
__device__ __forceinline__ float bf2f(unsigned short v) {
    return __uint_as_float(((unsigned int)v) << 16);
}

struct KParams {
    const float *t_in, *x_h, *x_hv, *bond, *em_hv, *em_hh, *amask;
    const float *W1, *b1, *W2, *b2, *Wc1, *bc1, *Wc2, *Wn1, *bn1, *Wn2, *bn2;
    const int *pep, *lab_hv, *lab_h, *pos_hv, *pos_h, *ehh, *bound;
    float *feat_h, *x, *x0h, *emk, *ebd, *agg0, *hiW1, *hjW1, *out;
    int *erow, *ecol;
    unsigned short *Wp;
    int *bar;
};

// Device-scope grid barrier, cache-friendly version.
// R7 lesson: ACQUIRE polls emit a buffer_inv (L1+L2 invalidate) on EVERY
// iteration -> waiting blocks continuously wiped the XCD L2 that working
// blocks relied on (FETCH_SIZE 10 MB -> 457 MB, 4.4x slowdown).
// Fix: RELAXED polls (still coherent -- atomics resolve at the coherence
// point -- but no cache invalidation), then ONE acquire + fence at exit.
__device__ __forceinline__ void gsync(int* bar, int idx)
{
    __syncthreads();
    if (threadIdx.x == 0) {
        __threadfence();   // release: write back this block's stores
        __hip_atomic_fetch_add(&bar[idx], 1, __ATOMIC_RELEASE, __HIP_MEMORY_SCOPE_AGENT);
        while (__hip_atomic_load(&bar[idx], __ATOMIC_RELAXED, __HIP_MEMORY_SCOPE_AGENT) < NBLK_)
            __builtin_amdgcn_s_sleep(16);
        // single acquire: invalidate stale lines ONCE, after everyone arrived
        (void)__hip_atomic_load(&bar[idx], __ATOMIC_ACQUIRE, __HIP_MEMORY_SCOPE_AGENT);
        __threadfence();
    }
    __syncthreads();
}

// shared-memory overlays (one 24.6 KB buffer reused by all phases)
struct EdgeSm {
    unsigned short m[TE_][MSTR_];  // 17408
    float partT[16][68];           // 4352
    float diff[TE_][4];            // 1024
    float db[TE_][2];              // 512
    float emk[TE_];                // 256
    int   ii[TE_];                 // 256
    int   jj[TE_];                 // 256
};                                 // 24064 B
struct UpdSm { float in[16][208]; float u[16][129]; };   // 21568 B
struct SortSm { int cnt[64]; int row[EHH_]; int col[EHH_]; float em[EHH_]; };

// ---------------- setup virtual blocks ----------------
#define HV_VB_    1600
#define PACK_VB_  256
#define EDGE_VB_  325
#define SORT_VB_  8
#define HROW_VB_  200
#define FEAT_VB_  125
#define ZERO_VB_  413      // 105600 float4 (both agg buffers)
#define XI_VB_    32
#define SETUP_VB_ (HV_VB_ + PACK_VB_ + EDGE_VB_ + SORT_VB_ + HROW_VB_ + FEAT_VB_ + ZERO_VB_ + XI_VB_)  // 2959

__device__ void setup_vblock(int blk, int t, const KParams& p, char* smem)
{
    if (blk < HV_VB_) {
        int g = blk*256 + t;                 // [0, 409600)
        int l = g / 204800;
        int r = g - l*204800;
        int node = r >> 7, col = r & 127;    // node = b*NH + nh
        int b = node / NH_;
        int label = p.lab_hv[node], pos = p.pos_hv[node];
        int aa = p.pep[b*15 + pos - 1];
        const float* W1l = p.W1 + l*EDIM_*HID_;
        float hj = W1l[(FDIM_ + label)*HID_ + col]
                 + W1l[(FDIM_ + 44 + aa)*HID_ + col]
                 + W1l[(FDIM_ + 64 + pos - 1)*HID_ + col];
        p.hjW1[(size_t)(1600 + l*1600 + node)*HID_ + col] = hj;
        return;
    }
    blk -= HV_VB_;
    if (blk < PACK_VB_) {
        int g = blk*256 + t;
        int idx = g & 16383;
        int lm  = g >> 14;
        int l = lm >> 1, mat = lm & 1;
        int j = idx & 7, q = (idx >> 3) & 3, n = (idx >> 5) & 127, kc = idx >> 12;
        int k = kc*32 + q*8 + j;
        const float* W = (mat == 0 ? p.W2 : p.Wc1) + l*HID_*HID_;
        p.Wp[g] = f2bf(W[k*HID_ + n]);
        return;
    }
    blk -= PACK_VB_;
    if (blk < EDGE_VB_) {
        int g = blk*256 + t;                  // [0, 83200)
        int b = g / NE_, e = g % NE_;
        if (e < EHH_) return;                 // hh edges handled by sort phase
        int k = e - EHH_;
        int r = k / NH_; int cc = k % NH_; int c = H_ + cc;
        p.erow[g] = r; p.ecol[g] = c;
        p.emk[g] = p.em_hv[(b*H_ + r)*NH_ + cc];
        p.ebd[g] = p.bond [(b*H_ + r)*NH_ + cc];
        return;
    }
    blk -= EDGE_VB_;
    if (blk < SORT_VB_) {
        // counting-sort the 400 hh edges of batch b by row
        int b = blk;
        SortSm* sm = (SortSm*)smem;
        __syncthreads();                      // protect any prior phase LDS use
        if (t < 64) sm->cnt[t] = 0;
        __syncthreads();
        for (int e = t; e < EHH_; e += 256) {
            int r = p.ehh[(b*EHH_ + e)*2 + 0];
            sm->row[e] = r;
            sm->col[e] = p.ehh[(b*EHH_ + e)*2 + 1];
            sm->em[e]  = p.em_hh[b*EHH_ + e];
            atomicAdd(&sm->cnt[r], 1);
        }
        __syncthreads();
        if (t == 0) {
            int acc = 0;
            for (int i = 0; i < H_; ++i) { int v = sm->cnt[i]; sm->cnt[i] = acc; acc += v; }
        }
        __syncthreads();
        for (int e = t; e < EHH_; e += 256) {
            int r = sm->row[e];
            int pos = atomicAdd(&sm->cnt[r], 1);
            int g = b*NE_ + pos;
            p.erow[g] = r; p.ecol[g] = sm->col[e]; p.emk[g] = sm->em[e]; p.ebd[g] = 0.0f;
        }
        __syncthreads();
        return;
    }
    blk -= SORT_VB_;
    if (blk < HROW_VB_) {
        // h-node layer-0 projections; fold b1 + t*w160 into hiW1
        int g = blk*256 + t;                 // [0, 51200)
        int node = g >> 7, col = g & 127;    // node = b*H + h
        int b = node / H_;
        int label = p.lab_h[node], pos = p.pos_h[node];
        int aa = p.pep[b*15 + pos - 1];
        const float* W1l = p.W1;
        float hi = W1l[label*HID_ + col]
                 + W1l[(44 + aa)*HID_ + col]
                 + W1l[(64 + pos - 1)*HID_ + col]
                 + p.b1[col]
                 + p.t_in[b] * W1l[160*HID_ + col];
        float hj = W1l[(FDIM_ + label)*HID_ + col]
                 + W1l[(FDIM_ + 44 + aa)*HID_ + col]
                 + W1l[(FDIM_ + 64 + pos - 1)*HID_ + col];
        int h = node % H_;
        #pragma unroll
        for (int s = 0; s < S_; ++s) {
            int row = (b*S_ + s)*H_ + h;
            p.hiW1[(size_t)row*HID_ + col] = hi;
            p.hjW1[(size_t)row*HID_ + col] = hj;
        }
        return;
    }
    blk -= HROW_VB_;
    if (blk < FEAT_VB_) {
        int g = blk*256 + t;                 // [0, 32000)
        int node = g / FS_, f = g % FS_;     // node = b*H + h
        int b = node / H_, h = node % H_;
        int label = p.lab_h[node], pos = p.pos_h[node];
        int aa = p.pep[b*15 + pos - 1];
        float v = 0.f;
        if (f < 44)      v = (f == label)          ? 1.0f : 0.0f;
        else if (f < 64) v = ((f - 44) == aa)      ? 1.0f : 0.0f;
        else if (f < 79) v = ((f - 64) == pos - 1) ? 1.0f : 0.0f;
        #pragma unroll
        for (int s = 0; s < S_; ++s)
            p.feat_h[((b*S_ + s)*H_ + h)*FS_ + f] = v;
        return;
    }
    blk -= FEAT_VB_;
    if (blk < ZERO_VB_) {
        int idx = blk*256 + t;
        if (idx < 105600) ((float4*)p.agg0)[idx] = make_float4(0.f, 0.f, 0.f, 0.f);
        return;
    }
    blk -= ZERO_VB_;
    {
        int g = blk*256 + t;
        if (g >= BS_*NN_) return;
        int bs = g / NN_, n = g % NN_;
        int b = bs / S_;
        if (n < H_) {
            int ba = p.bound[b*H_ + n];
            for (int d = 0; d < 3; ++d) {
                float v = p.x_h[(bs*H_ + n)*3 + d] + p.x_hv[(b*NH_ + ba)*3 + d];
                p.x[g*4 + d] = v;
                p.x0h[(bs*H_ + n)*4 + d] = v;
            }
        } else {
            int nh = n - H_;
            for (int d = 0; d < 3; ++d) p.x[g*4 + d] = p.x_hv[(b*NH_ + nh)*3 + d];
        }
    }
}

// ---------------- edge tile (64 edges) ----------------
__device__ void edge_tile(int tile, int t, const KParams& p, int l,
                          float* __restrict__ aggx, float* __restrict__ aggm,
                          char* smem)
{
    EdgeSm* sm = (EdgeSm*)smem;
    const int lane = t & 63, w = t >> 6;
    const int l15 = lane & 15, q = lane >> 4;

    __syncthreads();   // protect previous tile's LDS readers

    if (t < TE_) {
        int ge = tile*TE_ + t;
        int bs = ge / NE_;
        int e  = ge - bs*NE_;
        int b  = bs / S_;
        int row = p.erow[b*NE_ + e], col = p.ecol[b*NE_ + e];
        sm->ii[t] = bs*H_ + row;
        sm->jj[t] = (col < H_) ? (bs*H_ + col) : (1600 + l*1600 + b*NH_ + (col - H_));
        float dx0 = p.x[(bs*NN_ + row)*4 + 0] - p.x[(bs*NN_ + col)*4 + 0];
        float dx1 = p.x[(bs*NN_ + row)*4 + 1] - p.x[(bs*NN_ + col)*4 + 1];
        float dx2 = p.x[(bs*NN_ + row)*4 + 2] - p.x[(bs*NN_ + col)*4 + 2];
        sm->diff[t][0] = dx0; sm->diff[t][1] = dx1; sm->diff[t][2] = dx2;
        sm->db[t][0] = sqrtf(dx0*dx0 + dx1*dx1 + dx2*dx2);
        sm->db[t][1] = p.ebd[b*NE_ + e];
        sm->emk[t]   = p.emk[b*NE_ + e];
    }
    __syncthreads();

    const int mrow = w*16 + l15;

    // stage 1 (register-direct; b1 + t*w160 folded into hiW1)
    short8 afrag[4];
    {
        const float* W1l = p.W1 + l*EDIM_*HID_;
        int ri = sm->ii[mrow], rj = sm->jj[mrow];
        float dist = sm->db[mrow][0], bond = sm->db[mrow][1];
        const float* pi = p.hiW1 + (size_t)ri*HID_ + q*8;
        const float* pj = p.hjW1 + (size_t)rj*HID_ + q*8;
        #pragma unroll
        for (int kc = 0; kc < 4; ++kc) {
            int k0 = kc*32 + q*8;
            float4 a0 = *(const float4*)(pi + kc*32);
            float4 a1 = *(const float4*)(pi + kc*32 + 4);
            float4 c0 = *(const float4*)(pj + kc*32);
            float4 c1 = *(const float4*)(pj + kc*32 + 4);
            float4 wa0 = *(const float4*)(W1l + 158*HID_ + k0);
            float4 wa1 = *(const float4*)(W1l + 158*HID_ + k0 + 4);
            float4 wb0 = *(const float4*)(W1l + 159*HID_ + k0);
            float4 wb1 = *(const float4*)(W1l + 159*HID_ + k0 + 4);
            short8 fr;
            fr[0] = (short)f2bf(silu_(a0.x + c0.x + dist*wa0.x + bond*wb0.x));
            fr[1] = (short)f2bf(silu_(a0.y + c0.y + dist*wa0.y + bond*wb0.y));
            fr[2] = (short)f2bf(silu_(a0.z + c0.z + dist*wa0.z + bond*wb0.z));
            fr[3] = (short)f2bf(silu_(a0.w + c0.w + dist*wa0.w + bond*wb0.w));
            fr[4] = (short)f2bf(silu_(a1.x + c1.x + dist*wa1.x + bond*wb1.x));
            fr[5] = (short)f2bf(silu_(a1.y + c1.y + dist*wa1.y + bond*wb1.y));
            fr[6] = (short)f2bf(silu_(a1.z + c1.z + dist*wa1.z + bond*wb1.z));
            fr[7] = (short)f2bf(silu_(a1.w + c1.w + dist*wa1.w + bond*wb1.w));
            afrag[kc] = fr;
        }
    }

    // stage 2: m = silu(m1 @ W2 + b2) * emask
    {
        const unsigned short* Wp2 = p.Wp + (size_t)(l*2 + 0)*16384;
        const float* b2l = p.b2 + l*HID_;
        float em4[4];
        #pragma unroll
        for (int r = 0; r < 4; ++r) em4[r] = sm->emk[w*16 + q*4 + r];
        #pragma unroll
        for (int nt = 0; nt < 8; ++nt) {
            int colj = nt*16 + l15;
            float bias = b2l[colj];
            f32x4 c = {bias, bias, bias, bias};
            #pragma unroll
            for (int kc = 0; kc < 4; ++kc) {
                short8 bfrag = *(const short8*)&Wp2[((kc*128 + nt*16 + l15)*4 + q)*8];
                c = __builtin_amdgcn_mfma_f32_16x16x32_bf16(afrag[kc], bfrag, c, 0, 0, 0);
            }
            #pragma unroll
            for (int r = 0; r < 4; ++r)
                sm->m[w*16 + q*4 + r][colj] = f2bf(silu_(c[r]) * em4[r]);
        }
    }
    __builtin_amdgcn_wave_barrier();   // wave-private rows: ds_write before ds_read

    // stage 3: cw = silu(m @ Wc1 + bc1) @ Wc2
    {
        short8 af2[4];
        #pragma unroll
        for (int kc = 0; kc < 4; ++kc)
            af2[kc] = *(const short8*)&sm->m[mrow][kc*32 + q*8];
        const unsigned short* Wp3 = p.Wp + (size_t)(l*2 + 1)*16384;
        const float* bc1l = p.bc1 + l*HID_;
        const float* wc2l = p.Wc2 + l*HID_;
        float pp[4] = {0.f, 0.f, 0.f, 0.f};
        #pragma unroll
        for (int nt = 0; nt < 8; ++nt) {
            int colj = nt*16 + l15;
            float bias = bc1l[colj];
            f32x4 c = {bias, bias, bias, bias};
            #pragma unroll
            for (int kc = 0; kc < 4; ++kc) {
                short8 bfrag = *(const short8*)&Wp3[((kc*128 + nt*16 + l15)*4 + q)*8];
                c = __builtin_amdgcn_mfma_f32_16x16x32_bf16(af2[kc], bfrag, c, 0, 0, 0);
            }
            float wcv = wc2l[colj];
            #pragma unroll
            for (int r = 0; r < 4; ++r)
                pp[r] += silu_(c[r]) * wcv;
        }
        *(float4*)&sm->partT[l15][w*16 + q*4] = make_float4(pp[0], pp[1], pp[2], pp[3]);
    }
    __syncthreads();

    // aggregation: wave 0 = cw reduce + aggx; waves 1,2 = aggm
    if (t < TE_) {
        float cwv = 0.f;
        #pragma unroll
        for (int c = 0; c < 16; ++c) cwv += sm->partT[c][t];
        float run = 0.f; int ct = sm->ii[0];
        int d = lane & 3;
        for (int i2 = 0; i2 < TE_; ++i2) {
            float cwi = __shfl(cwv, i2, 64);
            int tg = sm->ii[i2];
            if (tg != ct) {
                if (lane < 3) atomicAdd(&aggx[(size_t)ct*4 + d], run);
                run = 0.f; ct = tg;
            }
            run += sm->diff[i2][d] * cwi;
        }
        if (lane < 3) atomicAdd(&aggx[(size_t)ct*4 + d], run);
    } else if (t < TE_ + HID_) {
        int j = t - TE_;
        float run = 0.f; int ct = sm->ii[0];
        for (int i2 = 0; i2 < TE_; ++i2) {
            int tg = sm->ii[i2];
            if (tg != ct) {
                atomicAdd(&aggm[(size_t)ct*HID_ + j], run);
                run = 0.f; ct = tg;
            }
            run += bf2f(sm->m[i2][j]);
        }
        atomicAdd(&aggm[(size_t)ct*HID_ + j], run);
    }
}

// ---------------- update (16 nodes per vblock, 256 threads) ----------------
__device__ void update_vblock(int vb, int t, const KParams& p, int l,
                              const float* __restrict__ aggm,
                              const float* __restrict__ aggx, char* smem)
{
    UpdSm* sm = (UpdSm*)smem;
    int node0 = vb * 16;                   // bs*H + h
    __syncthreads();
    for (int idx = t; idx < 16*208; idx += 256) {
        int g = idx / 208, k = idx - g*208;
        float v = 0.f;
        if (k < FDIM_)      v = p.feat_h[(node0 + g)*FS_ + k];
        else if (k < NDIM_) v = aggm[(size_t)(node0 + g)*HID_ + (k - FDIM_)];
        sm->in[g][k] = v;
    }
    __syncthreads();
    int half = t >> 7, ht = t & 127;
    int g0 = half * 8;
    const float* Wn1l = p.Wn1 + l*NDIM_*HID_;
    float acc[8];
    float bv = p.bn1[l*HID_ + ht];
    #pragma unroll
    for (int g = 0; g < 8; ++g) acc[g] = bv;
    for (int k = 0; k < NDIM_; ++k) {
        float wv = Wn1l[k*HID_ + ht];
        #pragma unroll
        for (int g = 0; g < 8; ++g) acc[g] += sm->in[g0 + g][k] * wv;
    }
    #pragma unroll
    for (int g = 0; g < 8; ++g) sm->u[g0 + g][ht] = silu_(acc[g]);
    __syncthreads();
    if (ht < FDIM_) {
        const float* Wn2l = p.Wn2 + l*HID_*FDIM_;
        float acc2[8];
        float b2v = p.bn2[l*FDIM_ + ht];
        #pragma unroll
        for (int g = 0; g < 8; ++g) acc2[g] = b2v;
        for (int k = 0; k < HID_; ++k) {
            float wv = Wn2l[k*FDIM_ + ht];
            #pragma unroll
            for (int g = 0; g < 8; ++g) acc2[g] += sm->u[g0 + g][k] * wv;
        }
        #pragma unroll
        for (int g = 0; g < 8; ++g) {
            float nf = sm->in[g0 + g][ht] + acc2[g];
            p.feat_h[(node0 + g0 + g)*FS_ + ht] = nf;
            sm->in[g0 + g][ht] = nf;
        }
    } else if (ht >= 96 && ht < 120) {
        int idx = ht - 96, g = idx / 3, d = idx % 3;
        int node = node0 + g0 + g;
        int bs = node / H_, h = node % H_;
        float xv = p.x[(bs*NN_ + h)*4 + d] + aggx[(size_t)node*4 + d];
        p.x[(bs*NN_ + h)*4 + d] = xv;
        if (l == L_ - 1) {
            int b = bs / S_;
            p.out[node*3 + d] = (xv - p.x0h[node*4 + d]) * p.amask[b*H_ + h];
        }
    }
    if (l != 0) return;
    __syncthreads();
    // next-layer W1 projections for the 16 updated h nodes (b1 + t*w160 folded)
    {
        const float* W1n = p.W1 + EDIM_*HID_;
        float w160 = W1n[160*HID_ + ht];
        float b1v  = p.b1[HID_ + ht];
        float hia[8], hja[8];
        #pragma unroll
        for (int g = 0; g < 8; ++g) { hia[g] = 0.f; hja[g] = 0.f; }
        for (int f = 0; f < FDIM_; ++f) {
            float wi = W1n[f*HID_ + ht];
            float wj = W1n[(FDIM_ + f)*HID_ + ht];
            #pragma unroll
            for (int g = 0; g < 8; ++g) {
                float v = sm->in[g0 + g][f];
                hia[g] += v * wi;
                hja[g] += v * wj;
            }
        }
        #pragma unroll
        for (int g = 0; g < 8; ++g) {
            int node = node0 + g0 + g;
            int b = (node / H_) / S_;
            p.hiW1[(size_t)node*HID_ + ht] = hia[g] + b1v + p.t_in[b]*w160;
            p.hjW1[(size_t)node*HID_ + ht] = hja[g];
        }
    }
}

// ---------------- the single persistent kernel (normal launch) ----------------
__global__ __launch_bounds__(256, 3) void k_fused(KParams p)
{
    __shared__ __align__(16) char smem[24576];
    const int t = threadIdx.x;

    for (int vb = blockIdx.x; vb < SETUP_VB_; vb += NBLK_)
        setup_vblock(vb, t, p, smem);
    gsync(p.bar, 0);

    for (int l = 0; l < L_; ++l) {
        float* aggx = p.agg0 + (size_t)l*AGGSTRIDE_;
        float* aggm = aggx + 6400;
        for (int vb = blockIdx.x; vb < NTILES_; vb += NBLK_)
            edge_tile(vb, t, p, l, aggx, aggm, smem);
        gsync(p.bar, 1 + 2*l);
        for (int vb = blockIdx.x; vb < 100; vb += NBLK_)
            update_vblock(vb, t, p, l, aggm, aggx, smem);
        if (l == 0) gsync(p.bar, 2);
    }
}

// ---------------- launch ----------------
extern "C" void kernel_launch(void* const* d_in, const int* in_sizes, int n_in,
                              void* d_out, int out_size, void* d_ws, size_t ws_size,
                              hipStream_t stream)
{
    float* ws = (float*)d_ws;
    KParams p;
    p.t_in  = (const float*)d_in[0];
    p.x_h   = (const float*)d_in[1];
    p.x_hv  = (const float*)d_in[2];
    p.bond  = (const float*)d_in[3];
    p.em_hv = (const float*)d_in[4];
    p.em_hh = (const float*)d_in[5];
    p.amask = (const float*)d_in[6];
    p.W1    = (const float*)d_in[7];
    p.b1    = (const float*)d_in[8];
    p.W2    = (const float*)d_in[9];
    p.b2    = (const float*)d_in[10];
    p.Wc1   = (const float*)d_in[11];
    p.bc1   = (const float*)d_in[12];
    p.Wc2   = (const float*)d_in[13];
    p.Wn1   = (const float*)d_in[14];
    p.bn1   = (const float*)d_in[15];
    p.Wn2   = (const float*)d_in[16];
    p.bn2   = (const float*)d_in[17];
    p.pep   = (const int*)d_in[18];
    p.lab_hv= (const int*)d_in[19];
    p.lab_h = (const int*)d_in[20];
    p.pos_hv= (const int*)d_in[21];
    p.pos_h = (const int*)d_in[22];
    p.ehh   = (const int*)d_in[23];
    p.bound = (const int*)d_in[24];
    p.feat_h = ws + OFF_FEATH;
    p.x      = ws + OFF_X;
    p.x0h    = ws + OFF_X0H;
    p.erow   = (int*)(ws + OFF_EROW);
    p.ecol   = (int*)(ws + OFF_ECOL);
    p.emk    = ws + OFF_EMASK;
    p.ebd    = ws + OFF_EBOND;
    p.agg0   = ws + OFF_AGG0;
    p.hiW1   = ws + OFF_HIW1;
    p.hjW1   = ws + OFF_HJW1;
    p.Wp     = (unsigned short*)(ws + OFF_WP);
    p.bar    = (int*)(ws + OFF_BAR);
    p.out    = (float*)d_out;

    // zero the global-barrier counters (ws is re-poisoned before every launch)
    hipMemsetAsync(p.bar, 0, 16*sizeof(int), stream);
    hipLaunchKernelGGL(k_fused, dim3(NBLK_), dim3(256), 0, stream, p);
}

// Round 9
// 427.031 us; speedup vs baseline: 4.6553x; 2.6665x over previous
//
#include <hip/hip_runtime.h>
#include <math.h>

// Problem constants
#define B_     8
#define S_     4
#define H_     50
#define NH_    200
#define EHH_   400
#define L_     2
#define HID_   128
#define FDIM_  79          // 44 + 20 + 15
#define EDIM_  161         // 2*FDIM + 3
#define NN_    250         // H + NH
#define NE_    10400       // EHH + H*NH
#define BS_    32          // B*S
#define TOTE_  (BS_*NE_)   // 332800
#define FS_    80          // feat row stride
#define TE_    64          // edges per block in edge kernel
#define MSTR_  136         // s_m stride in bf16 (128 + 8)
#define NDIM_  207         // FDIM + HID

// Workspace layout (float offsets)
#define OFF_FEATH  0         // BS*H*80 = 128000
#define OFF_X      128000    // BS*NN*4 = 32000
#define OFF_X0H    160000    // BS*H*4  = 6400
#define OFF_EROW   166400    // 83200 (int)
#define OFF_ECOL   249600    // 83200 (int)
#define OFF_EMASK  332800    // 83200
#define OFF_EBOND  416000    // 83200
#define OFF_AGG0   499200    // aggx0(6400) + aggm0(204800) = 211200
#define OFF_AGG1   710400    // 211200
#define OFF_HIW1   921600    // fp32 1600*128 (b1 + t*w160 folded in)
#define OFF_HJW1   1126400   // fp32 4800*128: [0,1600) h cur | [1600,3200) hv l0 | [3200,4800) hv l1
#define OFF_WP     1740800   // 65536 ushort
#define AGGSTRIDE_ 211200

typedef __attribute__((ext_vector_type(8))) short short8;
typedef __attribute__((ext_vector_type(4))) float f32x4;

__device__ __forceinline__ float silu_(float v) {
    return v * __builtin_amdgcn_rcpf(1.0f + __expf(-v));
}
__device__ __forceinline__ unsigned short f2bf(float f) {
    unsigned int u = __float_as_uint(f);
    unsigned int r = (u + 0x7fffu + ((u >> 16) & 1u)) >> 16;
    return (unsigned short)r;
}
__device__ __forceinline__ float bf2f(unsigned short v) {
    return __uint_as_float(((unsigned int)v) << 16);
}

// ================= fused setup =================
#define HV_BLKS_    1600   // heavy hjW1 both layers: 409600
#define PACK_BLKS_  256    // 65536
#define EDGE_BLKS_  325    // grid edges of 83200 (skip e<400)
#define SORT_BLKS_  8      // counting-sort hh edges by row, per b
#define HROW_BLKS_  200    // 400*128
#define FEAT_BLKS_  125    // 400*80
#define ZERO_BLKS_  207    // 52800 float4
#define XI_BLKS_    32     // 8000
#define SETUP_BLKS_ (HV_BLKS_ + PACK_BLKS_ + EDGE_BLKS_ + SORT_BLKS_ + HROW_BLKS_ + FEAT_BLKS_ + ZERO_BLKS_ + XI_BLKS_)

__global__ __launch_bounds__(256) void k_setup(
    const float* __restrict__ x_h, const float* __restrict__ x_hv,
    const int* __restrict__ bound,
    const int* __restrict__ ehh, const float* __restrict__ em_hh,
    const float* __restrict__ em_hv, const float* __restrict__ bond,
    const float* __restrict__ W1, const float* __restrict__ b1,
    const float* __restrict__ t_in,
    const float* __restrict__ W2, const float* __restrict__ Wc1,
    const int* __restrict__ lab_h, const int* __restrict__ pos_h,
    const int* __restrict__ lab_hv, const int* __restrict__ pos_hv,
    const int* __restrict__ pep,
    float* __restrict__ feat_h,
    float* __restrict__ x, float* __restrict__ x0h,
    int* __restrict__ erow, int* __restrict__ ecol,
    float* __restrict__ emk, float* __restrict__ ebd,
    float* __restrict__ hiW1, float* __restrict__ hjW1,
    float* __restrict__ agg0,
    unsigned short* __restrict__ Wp)
{
    int blk = blockIdx.x, t = threadIdx.x;
    if (blk < HV_BLKS_) {
        int g = blk*256 + t;                 // [0, 409600)
        int l = g / 204800;
        int r = g - l*204800;
        int node = r >> 7, col = r & 127;    // node = b*NH + nh
        int b = node / NH_;
        int label = lab_hv[node], pos = pos_hv[node];
        int aa = pep[b*15 + pos - 1];
        const float* W1l = W1 + l*EDIM_*HID_;
        float hj = W1l[(FDIM_ + label)*HID_ + col]
                 + W1l[(FDIM_ + 44 + aa)*HID_ + col]
                 + W1l[(FDIM_ + 64 + pos - 1)*HID_ + col];
        hjW1[(size_t)(1600 + l*1600 + node)*HID_ + col] = hj;
        return;
    }
    blk -= HV_BLKS_;
    if (blk < PACK_BLKS_) {
        int g = blk*256 + t;
        int idx = g & 16383;
        int lm  = g >> 14;
        int l = lm >> 1, mat = lm & 1;
        int j = idx & 7, q = (idx >> 3) & 3, n = (idx >> 5) & 127, kc = idx >> 12;
        int k = kc*32 + q*8 + j;
        const float* W = (mat == 0 ? W2 : Wc1) + l*HID_*HID_;
        Wp[g] = f2bf(W[k*HID_ + n]);
        return;
    }
    blk -= PACK_BLKS_;
    if (blk < EDGE_BLKS_) {
        int g = blk*256 + t;                  // [0, 83200)
        int b = g / NE_, e = g % NE_;
        if (e < EHH_) return;                 // hh edges handled by sort phase
        int k = e - EHH_;
        int r = k / NH_; int cc = k % NH_; int c = H_ + cc;
        erow[g] = r; ecol[g] = c;
        emk[g] = em_hv[(b*H_ + r)*NH_ + cc];
        ebd[g] = bond [(b*H_ + r)*NH_ + cc];
        return;
    }
    blk -= EDGE_BLKS_;
    if (blk < SORT_BLKS_) {
        // counting-sort the 400 hh edges of batch b by row -> long runs for agg
        int b = blk;
        __shared__ int scnt[64];
        __shared__ int srow[EHH_], scol[EHH_];
        __shared__ float sem[EHH_];
        if (t < 64) scnt[t] = 0;
        __syncthreads();
        for (int e = t; e < EHH_; e += 256) {
            int r = ehh[(b*EHH_ + e)*2 + 0];
            srow[e] = r;
            scol[e] = ehh[(b*EHH_ + e)*2 + 1];
            sem[e]  = em_hh[b*EHH_ + e];
            atomicAdd(&scnt[r], 1);
        }
        __syncthreads();
        if (t == 0) {
            int acc = 0;
            for (int i = 0; i < H_; ++i) { int v = scnt[i]; scnt[i] = acc; acc += v; }
        }
        __syncthreads();
        for (int e = t; e < EHH_; e += 256) {
            int r = srow[e];
            int pos = atomicAdd(&scnt[r], 1);
            int g = b*NE_ + pos;
            erow[g] = r; ecol[g] = scol[e]; emk[g] = sem[e]; ebd[g] = 0.0f;
        }
        return;
    }
    blk -= SORT_BLKS_;
    if (blk < HROW_BLKS_) {
        // h-node layer-0 projections; fold b1 and t*w160 into hiW1
        int g = blk*256 + t;                 // [0, 51200)
        int node = g >> 7, col = g & 127;    // node = b*H + h
        int b = node / H_;
        int label = lab_h[node], pos = pos_h[node];
        int aa = pep[b*15 + pos - 1];
        const float* W1l = W1;               // layer 0
        float hi = W1l[label*HID_ + col]
                 + W1l[(44 + aa)*HID_ + col]
                 + W1l[(64 + pos - 1)*HID_ + col]
                 + b1[col]
                 + t_in[b] * W1l[160*HID_ + col];
        float hj = W1l[(FDIM_ + label)*HID_ + col]
                 + W1l[(FDIM_ + 44 + aa)*HID_ + col]
                 + W1l[(FDIM_ + 64 + pos - 1)*HID_ + col];
        int h = node % H_;
        #pragma unroll
        for (int s = 0; s < S_; ++s) {
            int row = (b*S_ + s)*H_ + h;
            hiW1[(size_t)row*HID_ + col] = hi;
            hjW1[(size_t)row*HID_ + col] = hj;
        }
        return;
    }
    blk -= HROW_BLKS_;
    if (blk < FEAT_BLKS_) {
        int g = blk*256 + t;                 // [0, 32000)
        int node = g / FS_, f = g % FS_;     // node = b*H + h
        int b = node / H_, h = node % H_;
        int label = lab_h[node], pos = pos_h[node];
        int aa = pep[b*15 + pos - 1];
        float v = 0.f;
        if (f < 44)      v = (f == label)          ? 1.0f : 0.0f;
        else if (f < 64) v = ((f - 44) == aa)      ? 1.0f : 0.0f;
        else if (f < 79) v = ((f - 64) == pos - 1) ? 1.0f : 0.0f;
        #pragma unroll
        for (int s = 0; s < S_; ++s)
            feat_h[((b*S_ + s)*H_ + h)*FS_ + f] = v;
        return;
    }
    blk -= FEAT_BLKS_;
    if (blk < ZERO_BLKS_) {
        int idx = blk*256 + t;
        if (idx < 52800) ((float4*)agg0)[idx] = make_float4(0.f, 0.f, 0.f, 0.f);
        return;
    }
    blk -= ZERO_BLKS_;
    {
        int g = blk*256 + t;
        if (g >= BS_*NN_) return;
        int bs = g / NN_, n = g % NN_;
        int b = bs / S_;
        if (n < H_) {
            int ba = bound[b*H_ + n];
            for (int d = 0; d < 3; ++d) {
                float v = x_h[(bs*H_ + n)*3 + d] + x_hv[(b*NH_ + ba)*3 + d];
                x[g*4 + d] = v;
                x0h[(bs*H_ + n)*4 + d] = v;
            }
        } else {
            int nh = n - H_;
            for (int d = 0; d < 3; ++d) x[g*4 + d] = x_hv[(b*NH_ + nh)*3 + d];
        }
    }
}

// ============ per-layer: fused MFMA edge MLP + segment aggregation ============
__global__ __launch_bounds__(256, 4) void k_edge_mlp(
    const float* __restrict__ x, const float* __restrict__ hiW1,
    const float* __restrict__ hjW1,
    const int* __restrict__ erow, const int* __restrict__ ecol,
    const float* __restrict__ emk, const float* __restrict__ ebd,
    const float* __restrict__ W1,
    const float* __restrict__ b2, const float* __restrict__ bc1,
    const float* __restrict__ Wc2,
    const unsigned short* __restrict__ Wp, int l,
    float* __restrict__ aggx, float* __restrict__ aggm)
{
    __shared__ unsigned short s_m[TE_][MSTR_];   // 17408 B
    __shared__ float s_partT[16][68];            // 4352 B
    __shared__ float s_diff[TE_][4];
    __shared__ float s_db  [TE_][2];             // dist, bond
    __shared__ float s_emk [TE_];
    __shared__ int   s_ii  [TE_];                // bs*H + row
    __shared__ int   s_jj  [TE_];                // hjW1 row index

    const int t = threadIdx.x;
    const int lane = t & 63, w = t >> 6;
    const int l15 = lane & 15, q = lane >> 4;

    // ---- setup: per-edge scalars ----
    if (t < TE_) {
        int ge = blockIdx.x*TE_ + t;
        int bs = ge / NE_;
        int e  = ge - bs*NE_;
        int b  = bs / S_;
        int row = erow[b*NE_ + e], col = ecol[b*NE_ + e];
        s_ii[t] = bs*H_ + row;
        s_jj[t] = (col < H_) ? (bs*H_ + col) : (1600 + l*1600 + b*NH_ + (col - H_));
        float dx0 = x[(bs*NN_ + row)*4 + 0] - x[(bs*NN_ + col)*4 + 0];
        float dx1 = x[(bs*NN_ + row)*4 + 1] - x[(bs*NN_ + col)*4 + 1];
        float dx2 = x[(bs*NN_ + row)*4 + 2] - x[(bs*NN_ + col)*4 + 2];
        s_diff[t][0] = dx0; s_diff[t][1] = dx1; s_diff[t][2] = dx2;
        s_db[t][0] = sqrtf(dx0*dx0 + dx1*dx1 + dx2*dx2);
        s_db[t][1] = ebd[b*NE_ + e];
        s_emk[t]   = emk[b*NE_ + e];
    }
    __syncthreads();

    const int mrow = w*16 + l15;   // this lane's A-row (edge)

    // ---- stage 1 (register-direct): b1,t*w160 pre-folded into hiW1 ----
    short8 afrag[4];
    {
        const float* W1l = W1 + l*EDIM_*HID_;
        int ri = s_ii[mrow], rj = s_jj[mrow];
        float dist = s_db[mrow][0], bond = s_db[mrow][1];
        const float* pi = hiW1 + (size_t)ri*HID_ + q*8;
        const float* pj = hjW1 + (size_t)rj*HID_ + q*8;
        #pragma unroll
        for (int kc = 0; kc < 4; ++kc) {
            int k0 = kc*32 + q*8;
            float4 a0 = *(const float4*)(pi + kc*32);
            float4 a1 = *(const float4*)(pi + kc*32 + 4);
            float4 c0 = *(const float4*)(pj + kc*32);
            float4 c1 = *(const float4*)(pj + kc*32 + 4);
            float4 wa0 = *(const float4*)(W1l + 158*HID_ + k0);
            float4 wa1 = *(const float4*)(W1l + 158*HID_ + k0 + 4);
            float4 wb0 = *(const float4*)(W1l + 159*HID_ + k0);
            float4 wb1 = *(const float4*)(W1l + 159*HID_ + k0 + 4);
            short8 fr;
            fr[0] = (short)f2bf(silu_(a0.x + c0.x + dist*wa0.x + bond*wb0.x));
            fr[1] = (short)f2bf(silu_(a0.y + c0.y + dist*wa0.y + bond*wb0.y));
            fr[2] = (short)f2bf(silu_(a0.z + c0.z + dist*wa0.z + bond*wb0.z));
            fr[3] = (short)f2bf(silu_(a0.w + c0.w + dist*wa0.w + bond*wb0.w));
            fr[4] = (short)f2bf(silu_(a1.x + c1.x + dist*wa1.x + bond*wb1.x));
            fr[5] = (short)f2bf(silu_(a1.y + c1.y + dist*wa1.y + bond*wb1.y));
            fr[6] = (short)f2bf(silu_(a1.z + c1.z + dist*wa1.z + bond*wb1.z));
            fr[7] = (short)f2bf(silu_(a1.w + c1.w + dist*wa1.w + bond*wb1.w));
            afrag[kc] = fr;
        }
    }

    // ---- stage 2: m = silu(m1 @ W2 + b2) * emask  (bias in acc init) ----
    {
        const unsigned short* Wp2 = Wp + (size_t)(l*2 + 0)*16384;
        const float* b2l = b2 + l*HID_;
        float em4[4];
        #pragma unroll
        for (int r = 0; r < 4; ++r) em4[r] = s_emk[w*16 + q*4 + r];
        #pragma unroll
        for (int nt = 0; nt < 8; ++nt) {
            int colj = nt*16 + l15;
            float bias = b2l[colj];
            f32x4 c = {bias, bias, bias, bias};
            #pragma unroll
            for (int kc = 0; kc < 4; ++kc) {
                short8 bfrag = *(const short8*)&Wp2[((kc*128 + nt*16 + l15)*4 + q)*8];
                c = __builtin_amdgcn_mfma_f32_16x16x32_bf16(afrag[kc], bfrag, c, 0, 0, 0);
            }
            #pragma unroll
            for (int r = 0; r < 4; ++r)
                s_m[w*16 + q*4 + r][colj] = f2bf(silu_(c[r]) * em4[r]);
        }
    }
    __builtin_amdgcn_wave_barrier();   // wave-private rows: ds_write before ds_read

    // ---- stage 3: cw = silu(m @ Wc1 + bc1) @ Wc2 ----
    {
        short8 af2[4];
        #pragma unroll
        for (int kc = 0; kc < 4; ++kc)
            af2[kc] = *(const short8*)&s_m[mrow][kc*32 + q*8];
        const unsigned short* Wp3 = Wp + (size_t)(l*2 + 1)*16384;
        const float* bc1l = bc1 + l*HID_;
        const float* wc2l = Wc2 + l*HID_;
        float p[4] = {0.f, 0.f, 0.f, 0.f};
        #pragma unroll
        for (int nt = 0; nt < 8; ++nt) {
            int colj = nt*16 + l15;
            float bias = bc1l[colj];
            f32x4 c = {bias, bias, bias, bias};
            #pragma unroll
            for (int kc = 0; kc < 4; ++kc) {
                short8 bfrag = *(const short8*)&Wp3[((kc*128 + nt*16 + l15)*4 + q)*8];
                c = __builtin_amdgcn_mfma_f32_16x16x32_bf16(af2[kc], bfrag, c, 0, 0, 0);
            }
            float wcv = wc2l[colj];
            #pragma unroll
            for (int r = 0; r < 4; ++r)
                p[r] += silu_(c[r]) * wcv;
        }
        *(float4*)&s_partT[l15][w*16 + q*4] = make_float4(p[0], p[1], p[2], p[3]);
    }
    __syncthreads();

    // ---- aggregation (R4 layout — measured clean: 0.33M conflicts, 10 MB writes):
    // wave 0: cw reduce + aggx via shuffle; waves 1,2: aggm full 64-edge scans ----
    if (t < TE_) {
        float cwv = 0.f;
        #pragma unroll
        for (int c = 0; c < 16; ++c) cwv += s_partT[c][t];
        float run = 0.f; int ct = s_ii[0];
        int d = lane & 3;                       // lanes 0..2 meaningful
        for (int i2 = 0; i2 < TE_; ++i2) {
            float cwi = __shfl(cwv, i2, 64);
            int tg = s_ii[i2];
            if (tg != ct) {
                if (lane < 3) atomicAdd(&aggx[(size_t)ct*4 + d], run);
                run = 0.f; ct = tg;
            }
            run += s_diff[i2][d] * cwi;
        }
        if (lane < 3) atomicAdd(&aggx[(size_t)ct*4 + d], run);
    } else if (t < TE_ + HID_) {
        int j = t - TE_;
        float run = 0.f; int ct = s_ii[0];
        for (int i2 = 0; i2 < TE_; ++i2) {
            int tg = s_ii[i2];
            if (tg != ct) {
                atomicAdd(&aggm[(size_t)ct*HID_ + j], run);
                run = 0.f; ct = tg;
            }
            run += bf2f(s_m[i2][j]);
        }
        atomicAdd(&aggm[(size_t)ct*HID_ + j], run);
    }
}

// ====== per-layer: node update (8 nodes/block) + next-layer W1 (folded) + out ======
__global__ __launch_bounds__(128) void k_update(
    float* __restrict__ feat_h, float* __restrict__ x,
    const float* __restrict__ aggm, const float* __restrict__ aggx,
    const float* __restrict__ Wn1, const float* __restrict__ bn1,
    const float* __restrict__ Wn2, const float* __restrict__ bn2, int l,
    const float* __restrict__ W1, const float* __restrict__ b1,
    const float* __restrict__ t_in,
    float* __restrict__ hiW1, float* __restrict__ hjW1,
    float* __restrict__ zbase, int do_w1,
    const float* __restrict__ x0h, const float* __restrict__ amask,
    float* __restrict__ out)
{
    if (blockIdx.x >= 200) {
        int z = blockIdx.x - 200;
        for (int idx = z*128 + threadIdx.x; idx < 52800; idx += 207*128)
            ((float4*)zbase)[idx] = make_float4(0.f, 0.f, 0.f, 0.f);
        return;
    }
    __shared__ float s_in[8][NDIM_ + 1];
    __shared__ float s_u[8][HID_ + 1];
    int node0 = blockIdx.x * 8;            // bs*H + h
    int t = threadIdx.x;
    for (int idx = t; idx < 8*(NDIM_ + 1); idx += 128) {
        int g = idx / (NDIM_ + 1), k = idx % (NDIM_ + 1);
        float v = 0.f;
        if (k < FDIM_)      v = feat_h[(node0 + g)*FS_ + k];
        else if (k < NDIM_) v = aggm[(size_t)(node0 + g)*HID_ + (k - FDIM_)];
        s_in[g][k] = v;
    }
    __syncthreads();
    const float* Wn1l = Wn1 + l*NDIM_*HID_;
    float acc[8];
    float bv = bn1[l*HID_ + t];
    #pragma unroll
    for (int g = 0; g < 8; ++g) acc[g] = bv;
    for (int k = 0; k < NDIM_; ++k) {
        float wv = Wn1l[k*HID_ + t];
        #pragma unroll
        for (int g = 0; g < 8; ++g) acc[g] += s_in[g][k] * wv;
    }
    #pragma unroll
    for (int g = 0; g < 8; ++g) s_u[g][t] = silu_(acc[g]);
    __syncthreads();
    if (t < FDIM_) {
        const float* Wn2l = Wn2 + l*HID_*FDIM_;
        float acc2[8];
        float b2v = bn2[l*FDIM_ + t];
        #pragma unroll
        for (int g = 0; g < 8; ++g) acc2[g] = b2v;
        for (int k = 0; k < HID_; ++k) {
            float wv = Wn2l[k*FDIM_ + t];
            #pragma unroll
            for (int g = 0; g < 8; ++g) acc2[g] += s_u[g][k] * wv;
        }
        #pragma unroll
        for (int g = 0; g < 8; ++g) {
            float nf = s_in[g][t] + acc2[g];
            feat_h[(node0 + g)*FS_ + t] = nf;
            s_in[g][t] = nf;
        }
    } else if (t >= 96 && t < 120) {
        int idx = t - 96, g = idx / 3, d = idx % 3;
        int node = node0 + g;
        int bs = node / H_, h = node % H_;
        float xv = x[(bs*NN_ + h)*4 + d] + aggx[node*4 + d];
        x[(bs*NN_ + h)*4 + d] = xv;
        if (!do_w1) {
            int b = bs / S_;
            out[node*3 + d] = (xv - x0h[node*4 + d]) * amask[b*H_ + h];
        }
    }
    if (!do_w1) return;
    __syncthreads();
    // ---- next-layer W1 projections (fold b1 + t*w160 into hiW1) ----
    {
        const float* W1n = W1 + (l + 1)*EDIM_*HID_;
        float w160 = W1n[160*HID_ + t];
        float b1v  = b1[(l + 1)*HID_ + t];
        float hia[8], hja[8];
        #pragma unroll
        for (int g = 0; g < 8; ++g) { hia[g] = 0.f; hja[g] = 0.f; }
        for (int f = 0; f < FDIM_; ++f) {
            float wi = W1n[f*HID_ + t];
            float wj = W1n[(FDIM_ + f)*HID_ + t];
            #pragma unroll
            for (int g = 0; g < 8; ++g) {
                float v = s_in[g][f];
                hia[g] += v * wi;
                hja[g] += v * wj;
            }
        }
        #pragma unroll
        for (int g = 0; g < 8; ++g) {
            int node = node0 + g;
            int b = (node / H_) / S_;
            hiW1[(size_t)node*HID_ + t] = hia[g] + b1v + t_in[b]*w160;
            hjW1[(size_t)node*HID_ + t] = hja[g];
        }
    }
}

// ---------------- launch ----------------
extern "C" void kernel_launch(void* const* d_in, const int* in_sizes, int n_in,
                              void* d_out, int out_size, void* d_ws, size_t ws_size,
                              hipStream_t stream)
{
    const float* t_in  = (const float*)d_in[0];
    const float* x_h   = (const float*)d_in[1];
    const float* x_hv  = (const float*)d_in[2];
    const float* bond  = (const float*)d_in[3];
    const float* em_hv = (const float*)d_in[4];
    const float* em_hh = (const float*)d_in[5];
    const float* amask = (const float*)d_in[6];
    const float* W1    = (const float*)d_in[7];
    const float* b1    = (const float*)d_in[8];
    const float* W2    = (const float*)d_in[9];
    const float* b2    = (const float*)d_in[10];
    const float* Wc1   = (const float*)d_in[11];
    const float* bc1   = (const float*)d_in[12];
    const float* Wc2   = (const float*)d_in[13];
    const float* Wn1   = (const float*)d_in[14];
    const float* bn1   = (const float*)d_in[15];
    const float* Wn2   = (const float*)d_in[16];
    const float* bn2   = (const float*)d_in[17];
    const int* pep     = (const int*)d_in[18];
    const int* lab_hv  = (const int*)d_in[19];
    const int* lab_h   = (const int*)d_in[20];
    const int* pos_hv  = (const int*)d_in[21];
    const int* pos_h   = (const int*)d_in[22];
    const int* ehh     = (const int*)d_in[23];
    const int* bound   = (const int*)d_in[24];

    float* ws     = (float*)d_ws;
    float* feat_h = ws + OFF_FEATH;
    float* x      = ws + OFF_X;
    float* x0h    = ws + OFF_X0H;
    int*   erow   = (int*)(ws + OFF_EROW);
    int*   ecol   = (int*)(ws + OFF_ECOL);
    float* emk    = ws + OFF_EMASK;
    float* ebd    = ws + OFF_EBOND;
    float* hiW1   = ws + OFF_HIW1;
    float* hjW1   = ws + OFF_HJW1;
    unsigned short* Wp = (unsigned short*)(ws + OFF_WP);

    hipLaunchKernelGGL(k_setup, dim3(SETUP_BLKS_), dim3(256), 0, stream,
                       x_h, x_hv, bound, ehh, em_hh, em_hv, bond,
                       W1, b1, t_in, W2, Wc1,
                       lab_h, pos_h, lab_hv, pos_hv, pep,
                       feat_h, x, x0h, erow, ecol, emk, ebd,
                       hiW1, hjW1, ws + OFF_AGG0, Wp);

    for (int l = 0; l < L_; ++l) {
        float* aggx_l = ws + OFF_AGG0 + (size_t)l*AGGSTRIDE_;
        float* aggm_l = aggx_l + 6400;
        hipLaunchKernelGGL(k_edge_mlp, dim3(TOTE_/TE_), dim3(256), 0, stream,
                           x, hiW1, hjW1, erow, ecol, emk, ebd,
                           W1, b2, bc1, Wc2, Wp, l, aggx_l, aggm_l);
        int do_w1 = (l == 0);
        float* zbase = ws + OFF_AGG0 + (size_t)(l + 1)*AGGSTRIDE_;
        hipLaunchKernelGGL(k_update, dim3(do_w1 ? 407 : 200), dim3(128), 0, stream,
                           feat_h, x, aggm_l, aggx_l, Wn1, bn1, Wn2, bn2, l,
                           W1, b1, t_in, hiW1, hjW1,
                           do_w1 ? zbase : (ws + OFF_AGG0), do_w1,
                           x0h, amask, (float*)d_out);
    }
}